// Round 5
// baseline (1249.730 us; speedup 1.0000x reference)
//
#include <hip/hip_runtime.h>
#include <hip/hip_bf16.h>

typedef __bf16 bf16;
typedef __bf16 bf16x8 __attribute__((ext_vector_type(8)));
typedef float f32x4 __attribute__((ext_vector_type(4)));
typedef unsigned int u32x4 __attribute__((ext_vector_type(4)));

#define B_SZ 32
#define T_SZ 64
#define H_SZ 512
#define V_SZ 32000
#define NWG_REC 8
#define NWG_TOT 64

__device__ __forceinline__ float sigmoidf_(float v) { return 1.0f / (1.0f + expf(-v)); }

__device__ __forceinline__ bf16x8 cvt8(const float* __restrict__ p) {
  float4 a = *(const float4*)p;
  float4 b = *(const float4*)(p + 4);
  bf16x8 o;
  o[0] = (bf16)a.x; o[1] = (bf16)a.y; o[2] = (bf16)a.z; o[3] = (bf16)a.w;
  o[4] = (bf16)b.x; o[5] = (bf16)b.y; o[6] = (bf16)b.z; o[7] = (bf16)b.w;
  return o;
}

// ---- LLC-coherent primitives (bypass L1/L2 via sc0 sc1) ----
#define GLD(dst, base, off) \
  asm volatile("global_load_dwordx4 %0, %1, off offset:" off " sc0 sc1" \
               : "=v"(dst) : "v"(base))
#define LOADALL(af, base) do { \
  GLD(af[0],  base, "0");   GLD(af[1],  base, "64");  GLD(af[2],  base, "128"); GLD(af[3],  base, "192"); \
  GLD(af[4],  base, "256"); GLD(af[5],  base, "320"); GLD(af[6],  base, "384"); GLD(af[7],  base, "448"); \
  GLD(af[8],  base, "512"); GLD(af[9],  base, "576"); GLD(af[10], base, "640"); GLD(af[11], base, "704"); \
  GLD(af[12], base, "768"); GLD(af[13], base, "832"); GLD(af[14], base, "896"); GLD(af[15], base, "960"); \
} while (0)

#define GST2(base, off, val) do { \
  unsigned int w_ = (unsigned int)__builtin_bit_cast(unsigned short, (bf16)(val)); \
  asm volatile("global_store_short %0, %1, off offset:" off " sc0 sc1" \
               :: "v"(base), "v"(w_) : "memory"); \
} while (0)

__device__ __forceinline__ int llc_poll(const int* p) {
  int r;
  asm volatile("global_load_dword %0, %1, off sc0 sc1\n\ts_waitcnt vmcnt(0)"
               : "=v"(r) : "v"(p) : "memory");
  return r;
}

// ---------------- prep: h0 init, counters, Wz/Wr/Wh h-part extract+cvt ----------------
__global__ void prep_k(const float* __restrict__ feat, bf16* __restrict__ h_g,
                       int* __restrict__ ctr,
                       const float* __restrict__ Wz, const float* __restrict__ Wr,
                       const float* __restrict__ Wh, bf16* __restrict__ dst) {
  int i = blockIdx.x * blockDim.x + threadIdx.x;   // 98304 threads
  int w = i >> 15;
  int rem = i & 32767;
  int n = rem >> 6;
  int k8 = (rem & 63) * 8;
  const float* W = (w == 0) ? Wz : (w == 1) ? Wr : Wh;
  *(bf16x8*)(dst + (long)w * 262144 + n * 512 + k8) = cvt8(W + (long)n * 1024 + 512 + k8);
  if (i < B_SZ * H_SZ) h_g[i] = (bf16)feat[i];
  if (i == 0) { ctr[0] = 0; ctr[64] = 0; }
}

// ---------------- 128x128 bf16-MFMA GEMM-BT: C = A @ B^T + bias (f32 out) ----------------
// AMODE 0: A bf16 [M,K], B = B0 (bf16 if !BF32). AMODE 1: A = cvt(emb[caps[m]]) f32,
//   B/bias selected per 512-col gate block from {B0,B1,B2} (f32, ldb).
template<int AMODE, bool BF32>
__global__ __launch_bounds__(256) void gemm_bt(
    const void* __restrict__ Av, const int* __restrict__ caps, const float* __restrict__ emb,
    const void* __restrict__ B0, const void* __restrict__ B1, const void* __restrict__ B2, int ldb,
    const float* __restrict__ bias0, const float* __restrict__ bias1, const float* __restrict__ bias2,
    float* __restrict__ C, long ldc, int K, int mtiles)
{
  __shared__ __align__(16) bf16 lA[128 * 32];
  __shared__ __align__(16) bf16 lB[128 * 32];
  const int tid  = threadIdx.x;
  const int lane = tid & 63;
  const int l15  = lane & 15;
  const int kb8  = (lane >> 4) * 8;
  const int wid  = tid >> 6;
  const int wm   = wid >> 1, wn = wid & 1;
  const int wg   = blockIdx.x;
  const int mtile = wg % mtiles, ntile = wg / mtiles;
  const int m0 = mtile * 128, n0 = ntile * 128;

  const void* Bv; const float* bias; int nb;
  if (AMODE == 1) {
    int wsel = n0 >> 9;
    Bv = wsel == 0 ? B0 : wsel == 1 ? B1 : B2;
    bias = wsel == 0 ? bias0 : wsel == 1 ? bias1 : bias2;
    nb = n0 & 511;
  } else { Bv = B0; bias = bias0; nb = n0; }

  f32x4 acc[4][4] = {};

  for (int k0 = 0; k0 < K; k0 += 32) {
    #pragma unroll
    for (int j = 0; j < 2; ++j) {
      int c = j * 256 + tid;          // 0..511
      int row = c >> 2;
      int kc = (c & 3) * 8;
      bf16x8 av;
      if (AMODE == 1) av = cvt8(emb + (long)caps[m0 + row] * K + k0 + kc);
      else            av = *(const bf16x8*)((const bf16*)Av + (long)(m0 + row) * K + k0 + kc);
      *(bf16x8*)&lA[row * 32 + kc] = av;
      bf16x8 bv;
      if (BF32) bv = cvt8((const float*)Bv + (long)(nb + row) * ldb + k0 + kc);
      else      bv = *(const bf16x8*)((const bf16*)Bv + (long)(nb + row) * ldb + k0 + kc);
      *(bf16x8*)&lB[row * 32 + kc] = bv;
    }
    __syncthreads();
    bf16x8 af[4], bfr[4];
    #pragma unroll
    for (int mf = 0; mf < 4; ++mf)
      af[mf] = *(const bf16x8*)&lA[(wm * 64 + mf * 16 + l15) * 32 + kb8];
    #pragma unroll
    for (int nf = 0; nf < 4; ++nf)
      bfr[nf] = *(const bf16x8*)&lB[(wn * 64 + nf * 16 + l15) * 32 + kb8];
    #pragma unroll
    for (int mf = 0; mf < 4; ++mf)
      #pragma unroll
      for (int nf = 0; nf < 4; ++nf)
        acc[mf][nf] = __builtin_amdgcn_mfma_f32_16x16x32_bf16(af[mf], bfr[nf], acc[mf][nf], 0, 0, 0);
    __syncthreads();
  }

  #pragma unroll
  for (int mf = 0; mf < 4; ++mf)
    #pragma unroll
    for (int nf = 0; nf < 4; ++nf)
      #pragma unroll
      for (int r = 0; r < 4; ++r) {
        int row = m0 + wm * 64 + mf * 16 + (lane >> 4) * 4 + r;
        int lc  = wn * 64 + nf * 16 + l15;
        C[(long)row * ldc + n0 + lc] = acc[mf][nf][r] + bias[nb + lc];
      }
}

// ---------------- persistent GRU recurrence: 8 rec wgs + 56 cvt wgs ----------------
// Rec: 64 waves; wave u: batch-half grp=u>>5 (rows grp*16..+15), cols (u&31)*16..+15.
// Per-wave barrier arrivals into per-group counters (no __syncthreads in loop).
__global__ __launch_bounds__(512, 2) void gru_rec(
    const float* __restrict__ X,        // [2048][1536] z|r|h x-preactivations (bias folded)
    const bf16* __restrict__ Wzh, const bf16* __restrict__ Wrh, const bf16* __restrict__ Whh, // [512][512]
    const float* __restrict__ feat,
    bf16* __restrict__ h_g, bf16* __restrict__ rh_g,
    bf16* __restrict__ hs, int* __restrict__ ctr,
    const float* __restrict__ fcw_src, bf16* __restrict__ fcw_dst, int do_cvt)
{
  const int tid = threadIdx.x;
  if (blockIdx.x >= NWG_REC) {
    if (do_cvt) {                       // fc_w f32->bf16 on otherwise-idle CUs
      long base = ((long)(blockIdx.x - NWG_REC) * 512 + tid) * 8;
      const long stride = (long)(NWG_TOT - NWG_REC) * 512 * 8;
      for (long i = base; i < (long)V_SZ * H_SZ; i += stride)
        *(bf16x8*)(fcw_dst + i) = cvt8(fcw_src + i);
    }
    return;
  }

  const int lane = tid & 63;
  const int u    = blockIdx.x * 8 + (tid >> 6);   // 0..63
  const int l15  = lane & 15;
  const int kb   = (lane >> 4) * 8;
  const int rq   = (lane >> 4) * 4;
  const int grp  = u >> 5;
  const int b0   = grp * 16;
  const int gcol = (u & 31) * 16 + l15;
  int* mctr = ctr + grp * 64;                     // 256B apart

  // pinned phase-1 weights (128 VGPRs); Whh streamed per phase-2
  u32x4 Bz[16], Br[16];
  #pragma unroll
  for (int kk = 0; kk < 16; ++kk) {
    Bz[kk] = *(const u32x4*)(Wzh + (long)gcol * 512 + kk * 32 + kb);
    Br[kk] = *(const u32x4*)(Wrh + (long)gcol * 512 + kk * 32 + kb);
  }
  const bf16* whbase = Whh + (long)gcol * 512 + kb;

  float hprev[4];
  #pragma unroll
  for (int r = 0; r < 4; ++r) hprev[r] = feat[(b0 + rq + r) * 512 + gcol];

  const float* xb = X + (long)(b0 + rq) * 64 * 1536 + gcol;  // +r*98304 +t*1536 (+0/512/1024)
  float xz[4], xr[4];
  #pragma unroll
  for (int r = 0; r < 4; ++r) {
    xz[r] = xb[r * 98304];
    xr[r] = xb[r * 98304 + 512];
  }

  const bf16* ah   = h_g  + (b0 + l15) * 512 + kb;
  const bf16* arh  = rh_g + (b0 + l15) * 512 + kb;
  bf16* rhst = rh_g + (b0 + rq) * 512 + gcol;
  bf16* hst  = h_g  + (b0 + rq) * 512 + gcol;
  bf16* hsst = hs + (long)(b0 + rq) * 64 * 512 + gcol;       // +r*32768 +t*512

  int tgt = 0;
  for (int t = 0; t < T_SZ; ++t) {
    // ---------- phase 1: z (regs) + r -> rh ----------
    u32x4 af[16];
    LOADALL(af, ah);
    asm volatile("s_waitcnt vmcnt(0)" ::: "memory");
    __builtin_amdgcn_sched_barrier(0);
    f32x4 ze = {}, re = {};
    #pragma unroll
    for (int kk = 0; kk < 16; ++kk) {
      bf16x8 a = __builtin_bit_cast(bf16x8, af[kk]);
      ze = __builtin_amdgcn_mfma_f32_16x16x32_bf16(a, __builtin_bit_cast(bf16x8, Bz[kk]), ze, 0, 0, 0);
      re = __builtin_amdgcn_mfma_f32_16x16x32_bf16(a, __builtin_bit_cast(bf16x8, Br[kk]), re, 0, 0, 0);
    }
    f32x4 zf;
    {
      float r0 = sigmoidf_(re[0] + xr[0]) * hprev[0];
      float r1 = sigmoidf_(re[1] + xr[1]) * hprev[1];
      float r2 = sigmoidf_(re[2] + xr[2]) * hprev[2];
      float r3 = sigmoidf_(re[3] + xr[3]) * hprev[3];
      GST2(rhst, "0", r0); GST2(rhst, "1024", r1); GST2(rhst, "2048", r2); GST2(rhst, "3072", r3);
      #pragma unroll
      for (int r = 0; r < 4; ++r) zf[r] = sigmoidf_(ze[r] + xz[r]);
    }
    asm volatile("s_waitcnt vmcnt(0)" ::: "memory");   // drain rh stores only
    __builtin_amdgcn_sched_barrier(0);
    tgt += 32;
    if (lane == 0) __hip_atomic_fetch_add(mctr, 1, __ATOMIC_RELAXED, __HIP_MEMORY_SCOPE_AGENT);
    __builtin_amdgcn_sched_barrier(0);
    while (llc_poll(mctr) < tgt) __builtin_amdgcn_s_sleep(1);
    __builtin_amdgcn_sched_barrier(0);

    // ---------- phase 2: h_tilde + blend ----------
    LOADALL(af, arh);
    float xh[4];
    #pragma unroll
    for (int r = 0; r < 4; ++r) xh[r] = xb[r * 98304 + t * 1536 + 1024];  // hides under af RT
    asm volatile("s_waitcnt vmcnt(0)" ::: "memory");
    __builtin_amdgcn_sched_barrier(0);
    f32x4 he = {};
    #pragma unroll
    for (int kk = 0; kk < 16; ++kk) {
      u32x4 bh = *(const u32x4*)(whbase + kk * 32);   // streamed (L1/L2)
      he = __builtin_amdgcn_mfma_f32_16x16x32_bf16(
          __builtin_bit_cast(bf16x8, af[kk]), __builtin_bit_cast(bf16x8, bh), he, 0, 0, 0);
    }
    #pragma unroll
    for (int r = 0; r < 4; ++r) {
      float ht = tanhf(he[r] + xh[r]);
      hprev[r] = hprev[r] + zf[r] * (ht - hprev[r]);  // (1-z)h + z*ht
    }
    GST2(hst, "0", hprev[0]); GST2(hst, "1024", hprev[1]);
    GST2(hst, "2048", hprev[2]); GST2(hst, "3072", hprev[3]);

    if (t + 1 < T_SZ) {
      asm volatile("s_waitcnt vmcnt(0)" ::: "memory"); // drain h stores only
      __builtin_amdgcn_sched_barrier(0);
      tgt += 32;
      if (lane == 0) __hip_atomic_fetch_add(mctr, 1, __ATOMIC_RELAXED, __HIP_MEMORY_SCOPE_AGENT);
      // spin-window deferred work: hs stores (cached) + next-step X prefetch
      #pragma unroll
      for (int r = 0; r < 4; ++r) hsst[r * 32768 + t * 512] = (bf16)hprev[r];
      #pragma unroll
      for (int r = 0; r < 4; ++r) {
        xz[r] = xb[r * 98304 + (t + 1) * 1536];
        xr[r] = xb[r * 98304 + (t + 1) * 1536 + 512];
      }
      __builtin_amdgcn_sched_barrier(0);
      while (llc_poll(mctr) < tgt) __builtin_amdgcn_s_sleep(1);
      __builtin_amdgcn_sched_barrier(0);
    } else {
      #pragma unroll
      for (int r = 0; r < 4; ++r) hsst[r * 32768 + t * 512] = (bf16)hprev[r];
    }
  }
}

// ---------------- host ----------------
extern "C" void kernel_launch(void* const* d_in, const int* in_sizes, int n_in,
                              void* d_out, int out_size, void* d_ws, size_t ws_size,
                              hipStream_t stream) {
  const float* feat = (const float*)d_in[0];
  const int*   caps = (const int*)d_in[1];
  const float* emb  = (const float*)d_in[2];
  const float* Wz_w = (const float*)d_in[3];
  const float* Wz_b = (const float*)d_in[4];
  const float* Wr_w = (const float*)d_in[5];
  const float* Wr_b = (const float*)d_in[6];
  const float* Wh_w = (const float*)d_in[7];
  const float* Wh_b = (const float*)d_in[8];
  const float* fc_w = (const float*)d_in[9];
  const float* fc_b = (const float*)d_in[10];
  float* out = (float*)d_out;

  char* ws = (char*)d_ws;
  float* X_all = (float*)(ws + 0);              // 12,582,912
  bf16*  h_g   = (bf16*) (ws + 12582912);       // 32,768
  bf16*  rh_g  = (bf16*) (ws + 12615680);       // 32,768
  bf16*  hs    = (bf16*) (ws + 12648448);       // 2,097,152
  bf16*  Whp   = (bf16*) (ws + 14745600);       // 1,572,864
  int*   ctr   = (int*)  (ws + 16318464);       // 512 B (two counters, 256B apart)
  bf16*  fcw16 = (bf16*) (ws + 16318976);       // 32,768,000 -> end 49,086,976
  const bool cvt_fc = (ws_size >= (size_t)49087000);

  prep_k<<<dim3(384), dim3(256), 0, stream>>>(feat, h_g, ctr, Wz_w, Wr_w, Wh_w, Whp);

  // fused x-projections (bias folded): X_all[m][0:512)=z, [512:1024)=r, [1024:1536)=h
  gemm_bt<1, true><<<dim3(192), dim3(256), 0, stream>>>(
      nullptr, caps, emb, Wz_w, Wr_w, Wh_w, 1024, Wz_b, Wr_b, Wh_b,
      X_all, 1536, 512, 16);

  gru_rec<<<dim3(NWG_TOT), dim3(512), 0, stream>>>(
      X_all, Whp, Whp + 262144, Whp + 524288, feat, h_g, rh_g, hs, ctr,
      fc_w, fcw16, cvt_fc ? 1 : 0);

  // logits: hs[2048,512](bf16) @ fc_w[32000,512]^T + fc_b -> f32 out
  if (cvt_fc)
    gemm_bt<0, false><<<dim3(4000), dim3(256), 0, stream>>>(
        hs, nullptr, nullptr, fcw16, nullptr, nullptr, 512, fc_b, nullptr, nullptr,
        out, 32000, 512, 16);
  else
    gemm_bt<0, true><<<dim3(4000), dim3(256), 0, stream>>>(
        hs, nullptr, nullptr, fc_w, nullptr, nullptr, 512, fc_b, nullptr, nullptr,
        out, 32000, 512, 16);
}

// Round 6
// 1091.107 us; speedup vs baseline: 1.1454x; 1.1454x over previous
//
#include <hip/hip_runtime.h>
#include <hip/hip_bf16.h>

typedef __bf16 bf16;
typedef __bf16 bf16x8 __attribute__((ext_vector_type(8)));
typedef float f32x4 __attribute__((ext_vector_type(4)));
typedef unsigned int u32x4 __attribute__((ext_vector_type(4)));

#define B_SZ 32
#define T_SZ 64
#define H_SZ 512
#define V_SZ 32000

__device__ __forceinline__ float sigmoidf_(float v) { return 1.0f / (1.0f + expf(-v)); }

__device__ __forceinline__ bf16x8 cvt8(const float* __restrict__ p) {
  float4 a = *(const float4*)p;
  float4 b = *(const float4*)(p + 4);
  bf16x8 o;
  o[0] = (bf16)a.x; o[1] = (bf16)a.y; o[2] = (bf16)a.z; o[3] = (bf16)a.w;
  o[4] = (bf16)b.x; o[5] = (bf16)b.y; o[6] = (bf16)b.z; o[7] = (bf16)b.w;
  return o;
}

// ---- LLC-coherent primitives (bypass L1/L2 via sc0 sc1). asm outputs are
// opaque to the compiler => values CANNOT be rematerialized (true pinning). ----
#define GLD(dst, base, off) \
  asm volatile("global_load_dwordx4 %0, %1, off offset:" off " sc0 sc1" \
               : "=v"(dst) : "v"(base))
#define LOADALL(af, base) do { \
  GLD(af[0],  base, "0");   GLD(af[1],  base, "64");  GLD(af[2],  base, "128"); GLD(af[3],  base, "192"); \
  GLD(af[4],  base, "256"); GLD(af[5],  base, "320"); GLD(af[6],  base, "384"); GLD(af[7],  base, "448"); \
  GLD(af[8],  base, "512"); GLD(af[9],  base, "576"); GLD(af[10], base, "640"); GLD(af[11], base, "704"); \
  GLD(af[12], base, "768"); GLD(af[13], base, "832"); GLD(af[14], base, "896"); GLD(af[15], base, "960"); \
} while (0)

#define GST2(base, off, val) do { \
  unsigned int w_ = (unsigned int)__builtin_bit_cast(unsigned short, (bf16)(val)); \
  asm volatile("global_store_short %0, %1, off offset:" off " sc0 sc1" \
               :: "v"(base), "v"(w_) : "memory"); \
} while (0)

#define WAITV  asm volatile("s_waitcnt vmcnt(0)" ::: "memory")
#define SCHEDB __builtin_amdgcn_sched_barrier(0)

__device__ __forceinline__ int llc_poll(const int* p) {
  int r;
  asm volatile("global_load_dword %0, %1, off sc0 sc1\n\ts_waitcnt vmcnt(0)"
               : "=v"(r) : "v"(p) : "memory");
  return r;
}

// ---------------- prep: h0 init, flags, Wz/Wr/Wh h-part extract+cvt ----------------
__global__ void prep_k(const float* __restrict__ feat, bf16* __restrict__ h_g,
                       int* __restrict__ ctr,
                       const float* __restrict__ Wz, const float* __restrict__ Wr,
                       const float* __restrict__ Wh, bf16* __restrict__ dst) {
  int i = blockIdx.x * blockDim.x + threadIdx.x;   // 98304 threads
  int w = i >> 15;
  int rem = i & 32767;
  int n = rem >> 6;
  int k8 = (rem & 63) * 8;
  const float* W = (w == 0) ? Wz : (w == 1) ? Wr : Wh;
  *(bf16x8*)(dst + (long)w * 262144 + n * 512 + k8) = cvt8(W + (long)n * 1024 + 512 + k8);
  if (i < B_SZ * H_SZ) h_g[i] = (bf16)feat[i];
  if (i < 128) ctr[i] = 0;
}

// ---------------- 128x128 bf16-MFMA GEMM-BT: C = A @ B^T + bias (f32 out) ----------------
// AMODE 0: A bf16 [M,K], B = B0. AMODE 1: A = cvt(emb[caps[m]]); B/bias per 512-col
// gate block from {B0,B1,B2}; blocks >= gemm_blocks run fc_w f32->bf16 cvt instead.
template<int AMODE, bool BF32>
__global__ __launch_bounds__(256) void gemm_bt(
    const void* __restrict__ Av, const int* __restrict__ caps, const float* __restrict__ emb,
    const void* __restrict__ B0, const void* __restrict__ B1, const void* __restrict__ B2, int ldb,
    const float* __restrict__ bias0, const float* __restrict__ bias1, const float* __restrict__ bias2,
    float* __restrict__ C, long ldc, int K, int mtiles,
    int gemm_blocks, const float* __restrict__ fcw_src, bf16* __restrict__ fcw_dst)
{
  __shared__ __align__(16) bf16 lA[128 * 32];
  __shared__ __align__(16) bf16 lB[128 * 32];
  const int tid  = threadIdx.x;

  if (AMODE == 1 && (int)blockIdx.x >= gemm_blocks) {   // fused fc_w cvt blocks
    long base = ((long)(blockIdx.x - gemm_blocks) * 256 + tid) * 8;
    const long stride = (long)128 * 256 * 8;
    for (long i = base; i < (long)V_SZ * H_SZ; i += stride)
      *(bf16x8*)(fcw_dst + i) = cvt8(fcw_src + i);
    return;
  }

  const int lane = tid & 63;
  const int l15  = lane & 15;
  const int kb8  = (lane >> 4) * 8;
  const int wid  = tid >> 6;
  const int wm   = wid >> 1, wn = wid & 1;
  const int wg   = blockIdx.x;
  const int mtile = wg % mtiles, ntile = wg / mtiles;
  const int m0 = mtile * 128, n0 = ntile * 128;

  const void* Bv; const float* bias; int nb;
  if (AMODE == 1) {
    int wsel = n0 >> 9;
    Bv = wsel == 0 ? B0 : wsel == 1 ? B1 : B2;
    bias = wsel == 0 ? bias0 : wsel == 1 ? bias1 : bias2;
    nb = n0 & 511;
  } else { Bv = B0; bias = bias0; nb = n0; }

  f32x4 acc[4][4] = {};

  for (int k0 = 0; k0 < K; k0 += 32) {
    #pragma unroll
    for (int j = 0; j < 2; ++j) {
      int c = j * 256 + tid;          // 0..511
      int row = c >> 2;
      int kc = (c & 3) * 8;
      bf16x8 av;
      if (AMODE == 1) av = cvt8(emb + (long)caps[m0 + row] * K + k0 + kc);
      else            av = *(const bf16x8*)((const bf16*)Av + (long)(m0 + row) * K + k0 + kc);
      *(bf16x8*)&lA[row * 32 + kc] = av;
      bf16x8 bv;
      if (BF32) bv = cvt8((const float*)Bv + (long)(nb + row) * ldb + k0 + kc);
      else      bv = *(const bf16x8*)((const bf16*)Bv + (long)(nb + row) * ldb + k0 + kc);
      *(bf16x8*)&lB[row * 32 + kc] = bv;
    }
    __syncthreads();
    bf16x8 af[4], bfr[4];
    #pragma unroll
    for (int mf = 0; mf < 4; ++mf)
      af[mf] = *(const bf16x8*)&lA[(wm * 64 + mf * 16 + l15) * 32 + kb8];
    #pragma unroll
    for (int nf = 0; nf < 4; ++nf)
      bfr[nf] = *(const bf16x8*)&lB[(wn * 64 + nf * 16 + l15) * 32 + kb8];
    #pragma unroll
    for (int mf = 0; mf < 4; ++mf)
      #pragma unroll
      for (int nf = 0; nf < 4; ++nf)
        acc[mf][nf] = __builtin_amdgcn_mfma_f32_16x16x32_bf16(af[mf], bfr[nf], acc[mf][nf], 0, 0, 0);
    __syncthreads();
  }

  #pragma unroll
  for (int mf = 0; mf < 4; ++mf)
    #pragma unroll
    for (int nf = 0; nf < 4; ++nf)
      #pragma unroll
      for (int r = 0; r < 4; ++r) {
        int row = m0 + wm * 64 + mf * 16 + (lane >> 4) * 4 + r;
        int lc  = wn * 64 + nf * 16 + l15;
        C[(long)row * ldc + n0 + lc] = acc[mf][nf][r] + bias[nb + lc];
      }
}

// ---------------- persistent GRU recurrence: 8 wgs x 512 thr ----------------
// Group grp = bid>>2 (batch rows grp*16..+15); sub = bid&3; wave w=tid>>6;
// col-owner u = sub*8+w owns cols u*16..u*16+15. Barrier: per-wg flag store
// (sc0sc1) + poll of 3 peer flags. NO atomics, NO L2 fences.
__global__ __launch_bounds__(512, 2) void gru_rec(
    const float* __restrict__ X,        // [2048][1536] z|r|h x-preactivations (bias folded)
    const bf16* __restrict__ Wzh, const bf16* __restrict__ Wrh, const bf16* __restrict__ Whh, // [512][512]
    const float* __restrict__ feat,
    bf16* __restrict__ h_g, bf16* __restrict__ rh_g,
    bf16* __restrict__ hs, int* __restrict__ ctr)
{
  const int tid  = threadIdx.x;
  const int lane = tid & 63;
  const int bid  = blockIdx.x;
  const int grp  = bid >> 2;
  const int sub  = bid & 3;
  const int u    = sub * 8 + (tid >> 6);          // col-owner 0..31
  const int l15  = lane & 15;
  const int kb   = (lane >> 4) * 8;
  const int rq   = (lane >> 4) * 4;
  const int b0   = grp * 16;
  const int gcol = u * 16 + l15;

  int* ctrg = ctr + grp * 64;                     // 4 flags per group, groups 256B apart
  int* myflag = ctrg + sub;
  const int* pf = (tid < 3) ? (ctrg + ((sub + 1 + tid) & 3)) : ctrg;

  // ---- pinned weights: opaque asm loads => un-rematerializable (128 VGPRs) ----
  u32x4 Bz[16], Br[16];
  LOADALL(Bz, Wzh + (long)gcol * 512 + kb);
  LOADALL(Br, Wrh + (long)gcol * 512 + kb);
  WAITV;
  const bf16* whbase = Whh + (long)gcol * 512 + kb;   // Bh streamed (cached)

  float hprev[4];
  #pragma unroll
  for (int r = 0; r < 4; ++r) hprev[r] = feat[(b0 + rq + r) * 512 + gcol];

  const float* xb = X + (long)(b0 + rq) * 64 * 1536 + gcol;  // +r*98304 +t*1536 (+0/512/1024)
  float xz[4], xr[4];
  #pragma unroll
  for (int r = 0; r < 4; ++r) {
    xz[r] = xb[r * 98304];
    xr[r] = xb[r * 98304 + 512];
  }

  const bf16* ah   = h_g  + (b0 + l15) * 512 + kb;
  const bf16* arh  = rh_g + (b0 + l15) * 512 + kb;
  bf16* rhst = rh_g + (b0 + rq) * 512 + gcol;
  bf16* hst  = h_g  + (b0 + rq) * 512 + gcol;
  bf16* hsst = hs + (long)(b0 + rq) * 64 * 512 + gcol;       // +r*32768 +t*512

  int tgt = 0;
  for (int t = 0; t < T_SZ; ++t) {
    // ---------- phase 1: z (regs) + r -> rh ----------
    u32x4 af[16];
    LOADALL(af, ah);
    float xh[4];
    #pragma unroll
    for (int r = 0; r < 4; ++r) xh[r] = xb[r * 98304 + t * 1536 + 1024];  // hides under af RT
    WAITV;
    SCHEDB;
    f32x4 ze = {}, re = {};
    #pragma unroll
    for (int kk = 0; kk < 16; ++kk) {
      bf16x8 a = __builtin_bit_cast(bf16x8, af[kk]);
      ze = __builtin_amdgcn_mfma_f32_16x16x32_bf16(a, __builtin_bit_cast(bf16x8, Bz[kk]), ze, 0, 0, 0);
      re = __builtin_amdgcn_mfma_f32_16x16x32_bf16(a, __builtin_bit_cast(bf16x8, Br[kk]), re, 0, 0, 0);
    }
    {
      float r0 = sigmoidf_(re[0] + xr[0]) * hprev[0];
      float r1 = sigmoidf_(re[1] + xr[1]) * hprev[1];
      float r2 = sigmoidf_(re[2] + xr[2]) * hprev[2];
      float r3 = sigmoidf_(re[3] + xr[3]) * hprev[3];
      GST2(rhst, "0", r0); GST2(rhst, "1024", r1); GST2(rhst, "2048", r2); GST2(rhst, "3072", r3);
    }
    WAITV;                       // exchange stores at LLC
    __syncthreads();             // all waves drained
    ++tgt;
    if (tid == 0)
      asm volatile("global_store_dword %0, %1, off sc0 sc1" :: "v"(myflag), "v"(tgt) : "memory");
    // deferred (spin window): z sigmoid
    f32x4 zf;
    #pragma unroll
    for (int r = 0; r < 4; ++r) zf[r] = sigmoidf_(ze[r] + xz[r]);
    if (tid < 3) {
      int v;
      do { v = llc_poll(pf); } while (v < tgt);
    }
    __syncthreads();

    // ---------- phase 2: h_tilde + blend ----------
    LOADALL(af, arh);
    WAITV;
    SCHEDB;
    f32x4 he = {};
    #pragma unroll
    for (int kk = 0; kk < 16; ++kk) {
      u32x4 bh = *(const u32x4*)(whbase + kk * 32);   // streamed via L1/L2
      he = __builtin_amdgcn_mfma_f32_16x16x32_bf16(
          __builtin_bit_cast(bf16x8, af[kk]), __builtin_bit_cast(bf16x8, bh), he, 0, 0, 0);
    }
    #pragma unroll
    for (int r = 0; r < 4; ++r) {
      float ht = tanhf(he[r] + xh[r]);
      hprev[r] = hprev[r] + zf[r] * (ht - hprev[r]);  // (1-z)h + z*ht
    }

    if (t + 1 < T_SZ) {
      GST2(hst, "0", hprev[0]); GST2(hst, "1024", hprev[1]);
      GST2(hst, "2048", hprev[2]); GST2(hst, "3072", hprev[3]);
      WAITV;
      __syncthreads();
      ++tgt;
      if (tid == 0)
        asm volatile("global_store_dword %0, %1, off sc0 sc1" :: "v"(myflag), "v"(tgt) : "memory");
      // deferred (spin window): hs stores + next-step X prefetch (cached)
      #pragma unroll
      for (int r = 0; r < 4; ++r) hsst[r * 32768 + t * 512] = (bf16)hprev[r];
      #pragma unroll
      for (int r = 0; r < 4; ++r) {
        xz[r] = xb[r * 98304 + (t + 1) * 1536];
        xr[r] = xb[r * 98304 + (t + 1) * 1536 + 512];
      }
      if (tid < 3) {
        int v;
        do { v = llc_poll(pf); } while (v < tgt);
      }
      __syncthreads();
    } else {
      #pragma unroll
      for (int r = 0; r < 4; ++r) hsst[r * 32768 + t * 512] = (bf16)hprev[r];
    }
  }
}

// ---------------- host ----------------
extern "C" void kernel_launch(void* const* d_in, const int* in_sizes, int n_in,
                              void* d_out, int out_size, void* d_ws, size_t ws_size,
                              hipStream_t stream) {
  const float* feat = (const float*)d_in[0];
  const int*   caps = (const int*)d_in[1];
  const float* emb  = (const float*)d_in[2];
  const float* Wz_w = (const float*)d_in[3];
  const float* Wz_b = (const float*)d_in[4];
  const float* Wr_w = (const float*)d_in[5];
  const float* Wr_b = (const float*)d_in[6];
  const float* Wh_w = (const float*)d_in[7];
  const float* Wh_b = (const float*)d_in[8];
  const float* fc_w = (const float*)d_in[9];
  const float* fc_b = (const float*)d_in[10];
  float* out = (float*)d_out;

  char* ws = (char*)d_ws;
  float* X_all = (float*)(ws + 0);              // 12,582,912
  bf16*  h_g   = (bf16*) (ws + 12582912);       // 32,768
  bf16*  rh_g  = (bf16*) (ws + 12615680);       // 32,768
  bf16*  hs    = (bf16*) (ws + 12648448);       // 2,097,152
  bf16*  Whp   = (bf16*) (ws + 14745600);       // 1,572,864
  int*   ctr   = (int*)  (ws + 16318464);       // 512 B flag area
  bf16*  fcw16 = (bf16*) (ws + 16318976);       // 32,768,000 -> end 49,086,976
  const bool cvt_fc = (ws_size >= (size_t)49087000);

  prep_k<<<dim3(384), dim3(256), 0, stream>>>(feat, h_g, ctr, Wz_w, Wr_w, Wh_w, Whp);

  // fused x-projections (192 gemm blocks) + fc_w cvt (128 blocks)
  gemm_bt<1, true><<<dim3(cvt_fc ? 320 : 192), dim3(256), 0, stream>>>(
      nullptr, caps, emb, Wz_w, Wr_w, Wh_w, 1024, Wz_b, Wr_b, Wh_b,
      X_all, 1536, 512, 16, 192, fc_w, fcw16);

  gru_rec<<<dim3(8), dim3(512), 0, stream>>>(
      X_all, Whp, Whp + 262144, Whp + 524288, feat, h_g, rh_g, hs, ctr);

  // logits: hs[2048,512](bf16) @ fc_w[32000,512]^T + fc_b -> f32 out
  if (cvt_fc)
    gemm_bt<0, false><<<dim3(4000), dim3(256), 0, stream>>>(
        hs, nullptr, nullptr, fcw16, nullptr, nullptr, 512, fc_b, nullptr, nullptr,
        out, 32000, 512, 16, 4000, nullptr, nullptr);
  else
    gemm_bt<0, true><<<dim3(4000), dim3(256), 0, stream>>>(
        hs, nullptr, nullptr, fc_w, nullptr, nullptr, 512, fc_b, nullptr, nullptr,
        out, 32000, 512, 16, 4000, nullptr, nullptr);
}

// Round 9
// 1078.038 us; speedup vs baseline: 1.1593x; 1.0121x over previous
//
#include <hip/hip_runtime.h>
#include <hip/hip_bf16.h>

typedef __bf16 bf16;
typedef __bf16 bf16x8 __attribute__((ext_vector_type(8)));
typedef float f32x4 __attribute__((ext_vector_type(4)));
typedef unsigned int u32x4 __attribute__((ext_vector_type(4)));

#define B_SZ 32
#define T_SZ 64
#define H_SZ 512
#define V_SZ 32000

__device__ __forceinline__ float sigmoidf_(float v) { return 1.0f / (1.0f + expf(-v)); }

__device__ __forceinline__ bf16x8 cvt8(const float* __restrict__ p) {
  float4 a = *(const float4*)p;
  float4 b = *(const float4*)(p + 4);
  bf16x8 o;
  o[0] = (bf16)a.x; o[1] = (bf16)a.y; o[2] = (bf16)a.z; o[3] = (bf16)a.w;
  o[4] = (bf16)b.x; o[5] = (bf16)b.y; o[6] = (bf16)b.z; o[7] = (bf16)b.w;
  return o;
}

// ---- LLC-coherent primitives (bypass L1/L2 via sc0 sc1) ----
#define GLD(dst, base, off) \
  asm volatile("global_load_dwordx4 %0, %1, off offset:" off " sc0 sc1" \
               : "=v"(dst) : "v"(base))
#define GST2(base, off, val) do { \
  unsigned int w_ = (unsigned int)__builtin_bit_cast(unsigned short, (bf16)(val)); \
  asm volatile("global_store_short %0, %1, off offset:" off " sc0 sc1" \
               :: "v"(base), "v"(w_) : "memory"); \
} while (0)
#define WAITV  asm volatile("s_waitcnt vmcnt(0)" ::: "memory")
#define SCHEDB __builtin_amdgcn_sched_barrier(0)

__device__ __forceinline__ int llc_poll(const int* p) {
  int r;
  asm volatile("global_load_dword %0, %1, off sc0 sc1\n\ts_waitcnt vmcnt(0)"
               : "=v"(r) : "v"(p) : "memory");
  return r;
}

// ---------------- prep: h0 init, flags, Wz/Wr/Wh h-part extract+cvt ----------------
__global__ void prep_k(const float* __restrict__ feat, bf16* __restrict__ h_g,
                       int* __restrict__ ctr,
                       const float* __restrict__ Wz, const float* __restrict__ Wr,
                       const float* __restrict__ Wh, bf16* __restrict__ dst) {
  int i = blockIdx.x * blockDim.x + threadIdx.x;   // 98304 threads
  int w = i >> 15;
  int rem = i & 32767;
  int n = rem >> 6;
  int k8 = (rem & 63) * 8;
  const float* W = (w == 0) ? Wz : (w == 1) ? Wr : Wh;
  *(bf16x8*)(dst + (long)w * 262144 + n * 512 + k8) = cvt8(W + (long)n * 1024 + 512 + k8);
  if (i < B_SZ * H_SZ) h_g[i] = (bf16)feat[i];
  if (i < 128) ctr[i] = 0;
}

// ---------------- 128x128 bf16-MFMA GEMM-BT: C = A @ B^T + bias (f32 out) ----------------
// AMODE 0: A bf16 [M,K], B = B0. AMODE 1: A = cvt(emb[caps[m]]); B/bias per 512-col
// gate block from {B0,B1,B2}; blocks >= gemm_blocks run fc_w f32->bf16 cvt instead.
template<int AMODE, bool BF32>
__global__ __launch_bounds__(256) void gemm_bt(
    const void* __restrict__ Av, const int* __restrict__ caps, const float* __restrict__ emb,
    const void* __restrict__ B0, const void* __restrict__ B1, const void* __restrict__ B2, int ldb,
    const float* __restrict__ bias0, const float* __restrict__ bias1, const float* __restrict__ bias2,
    float* __restrict__ C, long ldc, int K, int mtiles,
    int gemm_blocks, const float* __restrict__ fcw_src, bf16* __restrict__ fcw_dst)
{
  __shared__ __align__(16) bf16 lA[128 * 32];
  __shared__ __align__(16) bf16 lB[128 * 32];
  const int tid  = threadIdx.x;

  if (AMODE == 1 && (int)blockIdx.x >= gemm_blocks) {   // fused fc_w cvt blocks
    long base = ((long)(blockIdx.x - gemm_blocks) * 256 + tid) * 8;
    const long stride = (long)128 * 256 * 8;
    for (long i = base; i < (long)V_SZ * H_SZ; i += stride)
      *(bf16x8*)(fcw_dst + i) = cvt8(fcw_src + i);
    return;
  }

  const int lane = tid & 63;
  const int l15  = lane & 15;
  const int kb8  = (lane >> 4) * 8;
  const int wid  = tid >> 6;
  const int wm   = wid >> 1, wn = wid & 1;
  const int wg   = blockIdx.x;
  const int mtile = wg % mtiles, ntile = wg / mtiles;
  const int m0 = mtile * 128, n0 = ntile * 128;

  const void* Bv; const float* bias; int nb;
  if (AMODE == 1) {
    int wsel = n0 >> 9;
    Bv = wsel == 0 ? B0 : wsel == 1 ? B1 : B2;
    bias = wsel == 0 ? bias0 : wsel == 1 ? bias1 : bias2;
    nb = n0 & 511;
  } else { Bv = B0; bias = bias0; nb = n0; }

  f32x4 acc[4][4] = {};

  for (int k0 = 0; k0 < K; k0 += 32) {
    #pragma unroll
    for (int j = 0; j < 2; ++j) {
      int c = j * 256 + tid;          // 0..511
      int row = c >> 2;
      int kc = (c & 3) * 8;
      bf16x8 av;
      if (AMODE == 1) av = cvt8(emb + (long)caps[m0 + row] * K + k0 + kc);
      else            av = *(const bf16x8*)((const bf16*)Av + (long)(m0 + row) * K + k0 + kc);
      *(bf16x8*)&lA[row * 32 + kc] = av;
      bf16x8 bv;
      if (BF32) bv = cvt8((const float*)Bv + (long)(nb + row) * ldb + k0 + kc);
      else      bv = *(const bf16x8*)((const bf16*)Bv + (long)(nb + row) * ldb + k0 + kc);
      *(bf16x8*)&lB[row * 32 + kc] = bv;
    }
    __syncthreads();
    bf16x8 af[4], bfr[4];
    #pragma unroll
    for (int mf = 0; mf < 4; ++mf)
      af[mf] = *(const bf16x8*)&lA[(wm * 64 + mf * 16 + l15) * 32 + kb8];
    #pragma unroll
    for (int nf = 0; nf < 4; ++nf)
      bfr[nf] = *(const bf16x8*)&lB[(wn * 64 + nf * 16 + l15) * 32 + kb8];
    #pragma unroll
    for (int mf = 0; mf < 4; ++mf)
      #pragma unroll
      for (int nf = 0; nf < 4; ++nf)
        acc[mf][nf] = __builtin_amdgcn_mfma_f32_16x16x32_bf16(af[mf], bfr[nf], acc[mf][nf], 0, 0, 0);
    __syncthreads();
  }

  #pragma unroll
  for (int mf = 0; mf < 4; ++mf)
    #pragma unroll
    for (int nf = 0; nf < 4; ++nf)
      #pragma unroll
      for (int r = 0; r < 4; ++r) {
        int row = m0 + wm * 64 + mf * 16 + (lane >> 4) * 4 + r;
        int lc  = wn * 64 + nf * 16 + l15;
        C[(long)row * ldc + n0 + lc] = acc[mf][nf][r] + bias[nb + lc];
      }
}

// ---------------- persistent GRU recurrence: 8 wgs x 512 thr (R4 structure) ----------------
// Two INDEPENDENT barrier groups (batch rows 0-15 / 16-31): grp=bid>>2, sub=bid&3.
// Wave w=tid>>6; col-owner u=sub*8+w owns cols u*16..+15 for all 16 rows of its group.
// Barrier: own-flag sc0sc1 store + poll 3 peer flags (no atomics, no acquire).
// Weights streamed from L2 inside MFMA loop (128-VGPR budget, 2 blocks/CU).
__global__ __launch_bounds__(512, 2) void gru_rec(
    const float* __restrict__ X,        // [2048][1536] z|r|h x-preactivations (bias folded)
    const bf16* __restrict__ Wzh, const bf16* __restrict__ Wrh, const bf16* __restrict__ Whh,
    const float* __restrict__ feat,
    bf16* __restrict__ h_g, bf16* __restrict__ rh_g,
    bf16* __restrict__ hs, int* __restrict__ ctr)
{
  __shared__ __align__(16) char ldsb[16384];      // 16 rows x 1024 B, XOR-swizzled
  const int tid  = threadIdx.x;                   // 0..511
  const int lane = tid & 63;
  const int bid  = blockIdx.x;
  const int grp  = bid >> 2;                      // batch half
  const int sub  = bid & 3;
  const int u    = sub * 8 + (tid >> 6);          // col-owner 0..31
  const int l15  = lane & 15;
  const int kb   = (lane >> 4) * 8;
  const int rq   = (lane >> 4) * 4;
  const int b0   = grp * 16;
  const int gcol = u * 16 + l15;

  int* ctrg = ctr + grp * 64;                     // 4 flags per group, groups 256B apart
  int* myflag = ctrg + sub;
  const int* pf = (tid < 3) ? (ctrg + ((sub + 1 + tid) & 3)) : ctrg;

  // weight row bases (streamed per phase from L2)
  const bf16* wz = Wzh + (long)gcol * 512 + kb;
  const bf16* wr = Wrh + (long)gcol * 512 + kb;
  const bf16* wh = Whh + (long)gcol * 512 + kb;

  float hprev[4];
  #pragma unroll
  for (int r = 0; r < 4; ++r) hprev[r] = feat[(b0 + rq + r) * 512 + gcol];

  const float* xb = X + (long)(b0 + rq) * 64 * 1536 + gcol;  // +r*98304 +t*1536 (+0/512/1024)
  float xz[4], xr[4];
  #pragma unroll
  for (int r = 0; r < 4; ++r) {
    xz[r] = xb[r * 98304];
    xr[r] = xb[r * 98304 + 512];
  }

  // LDS staging: 512 threads x 2 x 16B chunks; row = byte/1024
  const bf16* hsrc0  = h_g  + b0 * 512 + tid * 8;
  const bf16* hsrc1  = hsrc0 + 4096;
  const bf16* rhsrc0 = rh_g + b0 * 512 + tid * 8;
  const bf16* rhsrc1 = rhsrc0 + 4096;
  const int soff0 = (tid * 16) ^ (((tid >> 6) & 7) << 4);
  const int soff1 = (8192 + tid * 16) ^ (((tid >> 6) & 7) << 4);  // (row+8)&7 == row&7
  const int fbase = (l15 * 1024 + (lane >> 4) * 16) ^ ((l15 & 7) << 4);

  bf16* rhst = rh_g + (b0 + rq) * 512 + gcol;
  bf16* hst  = h_g  + (b0 + rq) * 512 + gcol;
  bf16* hsst = hs + (long)(b0 + rq) * 64 * 512 + gcol;       // +r*32768 +t*512

  int tgt = 0;
  for (int t = 0; t < T_SZ; ++t) {
    // ---------- phase 1: stage h -> LDS; z (regs) + r -> rh ----------
    {
      u32x4 v0, v1;
      GLD(v0, hsrc0, "0"); GLD(v1, hsrc1, "0");
      WAITV;
      SCHEDB;
      *(u32x4*)(ldsb + soff0) = v0;
      *(u32x4*)(ldsb + soff1) = v1;
    }
    __syncthreads();
    f32x4 ze = {}, zo = {}, re = {}, ro = {};
    #pragma unroll
    for (int kk = 0; kk < 16; kk += 2) {
      bf16x8 a0 = *(const bf16x8*)(ldsb + (fbase ^ (kk * 64)));
      bf16x8 a1 = *(const bf16x8*)(ldsb + (fbase ^ ((kk + 1) * 64)));
      bf16x8 bz0 = *(const bf16x8*)(wz + kk * 32);
      bf16x8 br0 = *(const bf16x8*)(wr + kk * 32);
      bf16x8 bz1 = *(const bf16x8*)(wz + (kk + 1) * 32);
      bf16x8 br1 = *(const bf16x8*)(wr + (kk + 1) * 32);
      ze = __builtin_amdgcn_mfma_f32_16x16x32_bf16(a0, bz0, ze, 0, 0, 0);
      re = __builtin_amdgcn_mfma_f32_16x16x32_bf16(a0, br0, re, 0, 0, 0);
      zo = __builtin_amdgcn_mfma_f32_16x16x32_bf16(a1, bz1, zo, 0, 0, 0);
      ro = __builtin_amdgcn_mfma_f32_16x16x32_bf16(a1, br1, ro, 0, 0, 0);
    }
    {
      float r0 = sigmoidf_(re[0] + ro[0] + xr[0]) * hprev[0];
      float r1 = sigmoidf_(re[1] + ro[1] + xr[1]) * hprev[1];
      float r2 = sigmoidf_(re[2] + ro[2] + xr[2]) * hprev[2];
      float r3 = sigmoidf_(re[3] + ro[3] + xr[3]) * hprev[3];
      GST2(rhst, "0", r0); GST2(rhst, "1024", r1); GST2(rhst, "2048", r2); GST2(rhst, "3072", r3);
    }
    WAITV;                       // rh stores acked at LLC
    __syncthreads();             // all 8 waves drained + done reading LDS
    ++tgt;
    if (tid == 0)
      asm volatile("global_store_dword %0, %1, off sc0 sc1" :: "v"(myflag), "v"(tgt) : "memory");
    // spin-window deferred work: z sigmoid + xh loads for phase 2
    f32x4 zf;
    #pragma unroll
    for (int r = 0; r < 4; ++r) zf[r] = sigmoidf_(ze[r] + zo[r] + xz[r]);
    float xh[4];
    #pragma unroll
    for (int r = 0; r < 4; ++r) xh[r] = xb[r * 98304 + t * 1536 + 1024];
    if (tid < 3) {
      int v;
      do { v = llc_poll(pf); } while (v < tgt);
    }
    __syncthreads();

    // ---------- phase 2: stage rh -> LDS; h_tilde + blend ----------
    {
      u32x4 v0, v1;
      GLD(v0, rhsrc0, "0"); GLD(v1, rhsrc1, "0");
      WAITV;
      SCHEDB;
      *(u32x4*)(ldsb + soff0) = v0;
      *(u32x4*)(ldsb + soff1) = v1;
    }
    __syncthreads();
    f32x4 he = {}, ho = {};
    #pragma unroll
    for (int kk = 0; kk < 16; kk += 2) {
      bf16x8 a0 = *(const bf16x8*)(ldsb + (fbase ^ (kk * 64)));
      bf16x8 a1 = *(const bf16x8*)(ldsb + (fbase ^ ((kk + 1) * 64)));
      bf16x8 bh0 = *(const bf16x8*)(wh + kk * 32);
      bf16x8 bh1 = *(const bf16x8*)(wh + (kk + 1) * 32);
      he = __builtin_amdgcn_mfma_f32_16x16x32_bf16(a0, bh0, he, 0, 0, 0);
      ho = __builtin_amdgcn_mfma_f32_16x16x32_bf16(a1, bh1, ho, 0, 0, 0);
    }
    #pragma unroll
    for (int r = 0; r < 4; ++r) {
      float ht = tanhf(he[r] + ho[r] + xh[r]);
      hprev[r] = hprev[r] + zf[r] * (ht - hprev[r]);  // (1-z)h + z*ht
    }

    if (t + 1 < T_SZ) {
      GST2(hst, "0", hprev[0]); GST2(hst, "1024", hprev[1]);
      GST2(hst, "2048", hprev[2]); GST2(hst, "3072", hprev[3]);
      WAITV;                     // h stores acked at LLC
      __syncthreads();           // all waves drained + done reading LDS
      ++tgt;
      if (tid == 0)
        asm volatile("global_store_dword %0, %1, off sc0 sc1" :: "v"(myflag), "v"(tgt) : "memory");
      // spin-window deferred work: hs stores (cached) + next-step X prefetch
      #pragma unroll
      for (int r = 0; r < 4; ++r) hsst[r * 32768 + t * 512] = (bf16)hprev[r];
      #pragma unroll
      for (int r = 0; r < 4; ++r) {
        xz[r] = xb[r * 98304 + (t + 1) * 1536];
        xr[r] = xb[r * 98304 + (t + 1) * 1536 + 512];
      }
      if (tid < 3) {
        int v;
        do { v = llc_poll(pf); } while (v < tgt);
      }
      __syncthreads();
    } else {
      #pragma unroll
      for (int r = 0; r < 4; ++r) hsst[r * 32768 + t * 512] = (bf16)hprev[r];
    }
  }
}

// ---------------- host ----------------
extern "C" void kernel_launch(void* const* d_in, const int* in_sizes, int n_in,
                              void* d_out, int out_size, void* d_ws, size_t ws_size,
                              hipStream_t stream) {
  const float* feat = (const float*)d_in[0];
  const int*   caps = (const int*)d_in[1];
  const float* emb  = (const float*)d_in[2];
  const float* Wz_w = (const float*)d_in[3];
  const float* Wz_b = (const float*)d_in[4];
  const float* Wr_w = (const float*)d_in[5];
  const float* Wr_b = (const float*)d_in[6];
  const float* Wh_w = (const float*)d_in[7];
  const float* Wh_b = (const float*)d_in[8];
  const float* fc_w = (const float*)d_in[9];
  const float* fc_b = (const float*)d_in[10];
  float* out = (float*)d_out;

  char* ws = (char*)d_ws;
  float* X_all = (float*)(ws + 0);              // 12,582,912
  bf16*  h_g   = (bf16*) (ws + 12582912);       // 32,768
  bf16*  rh_g  = (bf16*) (ws + 12615680);       // 32,768
  bf16*  hs    = (bf16*) (ws + 12648448);       // 2,097,152
  bf16*  Whp   = (bf16*) (ws + 14745600);       // 1,572,864
  int*   ctr   = (int*)  (ws + 16318464);       // 512 B flag area
  bf16*  fcw16 = (bf16*) (ws + 16318976);       // 32,768,000 -> end 49,086,976
  const bool cvt_fc = (ws_size >= (size_t)49087000);

  prep_k<<<dim3(384), dim3(256), 0, stream>>>(feat, h_g, ctr, Wz_w, Wr_w, Wh_w, Whp);

  // fused x-projections (192 gemm blocks) + fc_w cvt (128 blocks)
  gemm_bt<1, true><<<dim3(cvt_fc ? 320 : 192), dim3(256), 0, stream>>>(
      nullptr, caps, emb, Wz_w, Wr_w, Wh_w, 1024, Wz_b, Wr_b, Wh_b,
      X_all, 1536, 512, 16, 192, fc_w, fcw16);

  gru_rec<<<dim3(8), dim3(512), 0, stream>>>(
      X_all, Whp, Whp + 262144, Whp + 524288, feat, h_g, rh_g, hs, ctr);

  // logits: hs[2048,512](bf16) @ fc_w[32000,512]^T + fc_b -> f32 out
  if (cvt_fc)
    gemm_bt<0, false><<<dim3(4000), dim3(256), 0, stream>>>(
        hs, nullptr, nullptr, fcw16, nullptr, nullptr, 512, fc_b, nullptr, nullptr,
        out, 32000, 512, 16, 4000, nullptr, nullptr);
  else
    gemm_bt<0, true><<<dim3(4000), dim3(256), 0, stream>>>(
        hs, nullptr, nullptr, fc_w, nullptr, nullptr, 512, fc_b, nullptr, nullptr,
        out, 32000, 512, 16, 4000, nullptr, nullptr);
}